// Round 3
// baseline (142.030 us; speedup 1.0000x reference)
//
#include <hip/hip_runtime.h>
#include <hip/hip_cooperative_groups.h>
#include <math.h>

namespace cg = cooperative_groups;

#define NN 30000
#define BB 16
#define DIST_C 5.0f
#define EPS_C 1e-6f
#define SCALE_C 0.17677669529663687f  // 1/sqrt(32)

#define NPB 32     // nodes per tile (8 threads/node, 256-thread blocks)
#define TPB 2      // tiles per block
#define GRID 469   // ceil(30000 / 64)

// workspace layout (float offsets)
#define WS_ZMIN  0      // 16 x uint (encoded float, final)
#define WS_ZMAX  16     // 16 x uint
#define WS_ZSUM  32     // 32 f  [b*2+s]
#define WS_PK    96     // 256 f [h*32+d]
#define WS_WC    352    // 1024 f [d*32+e]
#define WS_T     1376   // 8192 f [b*512 + (s*8+h)*32 + d]
#define WS_AKG   9568   // 8192 f
#define WS_AVG   17760  // 8192 f
#define WS_ZPART 25952  // GRID*32 uints: per-block {min[16], max[16]} partials

// phase bitmask
#define M_PRE 1
#define M_RED 2
#define M_A   4
#define M_B   8
#define M_C   16
#define M_ALL 31

__device__ __forceinline__ unsigned fencode(float f) {
    unsigned u = __float_as_uint(f);
    return (u & 0x80000000u) ? ~u : (u | 0x80000000u);
}
__device__ __forceinline__ float fdecode(unsigned c) {
    return __uint_as_float((c & 0x80000000u) ? (c ^ 0x80000000u) : ~c);
}
__device__ __forceinline__ float silu(float x) { return x / (1.0f + expf(-x)); }

// edge[s][k] = sin(bw_k*x_s)/(x_s+eps); bw_k = (k+1)*bw0. Chebyshev recurrence.
__device__ __forceinline__ void bessel_edges(float bw0, float x0, float x1, float edge[2][8]) {
    float xs[2]; xs[0] = x0; xs[1] = x1;
    #pragma unroll
    for (int s = 0; s < 2; ++s) {
        float x = xs[s];
        float inv = 1.0f / (x + EPS_C);
        float th = bw0 * x;
        float c2 = 2.0f * cosf(th);
        float skm1 = 0.0f;
        float sk = sinf(th);
        #pragma unroll
        for (int k = 0; k < 8; ++k) {
            edge[s][k] = sk * inv;
            float nx = c2 * sk - skm1;
            skm1 = sk;
            sk = nx;
        }
    }
}

__global__ __launch_bounds__(256, 2) void k_main(
    const float* __restrict__ pos, const int* __restrict__ batch,
    const float* __restrict__ nf, const float* __restrict__ bw,
    const float* __restrict__ W1_kd, const float* __restrict__ W1_vd,
    const float* __restrict__ W1_kg, const float* __restrict__ W1_vg,
    const float* __restrict__ init_dummy, const float* __restrict__ Wq_dummy,
    const float* __restrict__ Wdot, const float* __restrict__ W2_kd,
    const float* __restrict__ W2_vd, const float* __restrict__ W2_kg,
    const float* __restrict__ W2_vg, const float* __restrict__ Wq_graph,
    float* __restrict__ ws, float* __restrict__ out, int mode)
{
    __shared__ __align__(16) float Fl[TPB][NPB * 36];
    __shared__ float Lw[TPB][NPB * 17];
    __shared__ int   Lb[TPB][NPB];
    __shared__ __align__(16) float Pk[256];
    __shared__ __align__(16) float Wc[1024];
    __shared__ float W1kd[64], W1vd[64], W1kg[64], W1vg[64], zsl[32];
    __shared__ unsigned zl[16], zh[16];
    __shared__ float qvec[32], qWl[32];
    __shared__ float Tl[256], part[256], dn[32];

    const bool coop   = (mode == M_ALL);
    const bool do_pre = mode & M_PRE;
    const bool do_red = mode & M_RED;
    const bool do_a   = mode & M_A;
    const bool do_b   = mode & M_B;
    const bool do_c   = mode & M_C;

    int t = threadIdx.x;
    int li = t >> 3, g = t & 7;
    int lanebase = (t & 63) & 56;
    unsigned* wsu = (unsigned*)ws;

    // ---------------- prelude: per-node loads (PRE, A, C)
    float4 fv4[TPB]; float zreg[TPB]; int bseg[TPB]; bool val[TPB];
    float bw0 = 0.f;
    if (do_pre || do_a || do_c) {
        bw0 = bw[0];
        #pragma unroll
        for (int it = 0; it < TPB; ++it) {
            int n = (blockIdx.x * TPB + it) * NPB + li;
            val[it] = (n < NN);
            bseg[it] = 0; zreg[it] = 0.f;
            fv4[it] = make_float4(0.f, 0.f, 0.f, 0.f);
            if (val[it]) {
                bseg[it] = batch[n];
                fv4[it] = ((const float4*)nf)[n * 8 + g];
                ((float4*)(Fl[it] + li * 36))[g] = fv4[it];
                zreg[it] = pos[3 * n + 2];
                if (g == 0) Lb[it][li] = bseg[it];
            } else if (g == 0) Lb[it][li] = -1;
        }
    }

    // ---------------- PRE: zminmax partials + ws init duties
    if (do_pre) {
        if (t < 16) { zl[t] = 0xFFFFFFFFu; zh[t] = 0u; }
        __syncthreads();
        #pragma unroll
        for (int it = 0; it < TPB; ++it)
            if (val[it] && g == 0) {
                unsigned c = fencode(zreg[it]);
                atomicMin(&zl[bseg[it]], c);
                atomicMax(&zh[bseg[it]], c);
            }
        __syncthreads();
        if (t < 16) {
            wsu[WS_ZPART + blockIdx.x * 32 + t]      = zl[t];
            wsu[WS_ZPART + blockIdx.x * 32 + 16 + t] = zh[t];
        }
        int xb = blockIdx.x;
        if (xb >= 32 && xb < 48) {               // zero T (16 blocks x 512)
            int off = (xb - 32) * 512 + t;
            ws[WS_T + off] = 0.f; ws[WS_T + off + 256] = 0.f;
        } else if (xb == 48) {                   // zero ZSUM
            if (t < 32) ws[WS_ZSUM + t] = 0.f;
        } else if (xb == 49) {                   // Pk = W2_kd contracted with qW
            if (t < 32) {
                float acc = 0.f;
                for (int d = 0; d < 32; ++d) acc += init_dummy[d] * Wq_dummy[d * 32 + t];
                qvec[t] = acc;
            }
            __syncthreads();
            if (t < 32) {
                float acc = 0.f;
                for (int e = 0; e < 32; ++e) acc += qvec[e] * Wdot[e * 32 + t];
                qWl[t] = acc;
            }
            __syncthreads();
            {
                int h = t >> 5, d = t & 31;
                float acc = 0.f;
                for (int e = 0; e < 32; ++e) acc += W2_kd[h * 1024 + d * 32 + e] * qWl[e];
                ws[WS_PK + t] = acc;
            }
        } else if (xb >= 50 && xb < 54) {        // Wc = Wq_graph @ Wdot (4 blocks)
            int i = (xb - 50) * 256 + t;
            int d = i >> 5, e = i & 31;
            float acc = 0.f;
            for (int m = 0; m < 32; ++m) acc += Wq_graph[d * 32 + m] * Wdot[m * 32 + e];
            ws[WS_WC + i] = acc;
        }
    }
    if (coop) cg::this_grid().sync();

    // ---------------- RED: reduce zmin/zmax partials (16 blocks)
    if (do_red && blockIdx.x < 16) {
        int b = blockIdx.x;
        unsigned mn = 0xFFFFFFFFu, mx = 0u;
        for (int e = t; e < GRID; e += 256) {
            unsigned a = wsu[WS_ZPART + e * 32 + b];
            unsigned c = wsu[WS_ZPART + e * 32 + 16 + b];
            mn = (a < mn) ? a : mn;
            mx = (c > mx) ? c : mx;
        }
        if (t == 0) { zl[0] = 0xFFFFFFFFu; zh[0] = 0u; }
        __syncthreads();
        atomicMin(&zl[0], mn);
        atomicMax(&zh[0], mx);
        __syncthreads();
        if (t == 0) { wsu[WS_ZMIN + b] = zl[0]; wsu[WS_ZMAX + b] = zh[0]; }
    }
    if (coop) cg::this_grid().sync();

    // ---------------- stage weights + bessel (A, C)
    float edge[TPB][2][8];
    if (do_a || do_c) {
        Pk[t] = ws[WS_PK + t];
        for (int i = t; i < 1024; i += 256) Wc[i] = ws[WS_WC + i];
        if (t < 64) { W1kd[t] = W1_kd[t]; W1vd[t] = W1_vd[t]; W1kg[t] = W1_kg[t]; W1vg[t] = W1_vg[t]; }
        if (t < 32) zsl[t] = 0.f;
        __syncthreads();
        #pragma unroll
        for (int it = 0; it < TPB; ++it)
            if (val[it]) {
                float zmin = fdecode(wsu[WS_ZMIN + bseg[it]]);
                float zmax = fdecode(wsu[WS_ZMAX + bseg[it]]);
                bessel_edges(bw0, zreg[it] - zmin + DIST_C, zmax + DIST_C - zreg[it], edge[it]);
            }
    }

    // ---------------- A: s, e, zsum, T accumulation
    if (do_a) {
        #pragma unroll
        for (int it = 0; it < TPB; ++it) {
            if (val[it]) {
                float up[8];
                const float4* Pk4 = (const float4*)Pk;
                #pragma unroll
                for (int h = 0; h < 8; ++h) {
                    float4 p = Pk4[h * 8 + g];
                    up[h] = fv4[it].x * p.x + fv4[it].y * p.y + fv4[it].z * p.z + fv4[it].w * p.w;
                }
                float p0 = 0.f, p1 = 0.f;
                #pragma unroll
                for (int k = 0; k < 8; ++k) {
                    float w = W1kd[k * 8 + g];
                    p0 += edge[it][0][k] * w;
                    p1 += edge[it][1][k] * w;
                }
                float kd0 = silu(p0), kd1 = silu(p1);
                float sp0 = 0.f, sp1 = 0.f;
                #pragma unroll
                for (int h = 0; h < 8; ++h) {
                    sp0 += __shfl(kd0, lanebase + h, 64) * up[h];
                    sp1 += __shfl(kd1, lanebase + h, 64) * up[h];
                }
                #pragma unroll
                for (int m = 1; m < 8; m <<= 1) {
                    sp0 += __shfl_xor(sp0, m, 64);
                    sp1 += __shfl_xor(sp1, m, 64);
                }
                float ev0 = expf(sp0 * SCALE_C);
                float ev1 = expf(sp1 * SCALE_C);
                if (g == 0) {
                    atomicAdd(&zsl[bseg[it] * 2 + 0], ev0);
                    atomicAdd(&zsl[bseg[it] * 2 + 1], ev1);
                }
                float q0 = 0.f, q1 = 0.f;
                #pragma unroll
                for (int k = 0; k < 8; ++k) {
                    float w = W1vd[k * 8 + g];
                    q0 += edge[it][0][k] * w;
                    q1 += edge[it][1][k] * w;
                }
                Lw[it][li * 17 + g]     = ev0 * silu(q0);
                Lw[it][li * 17 + 8 + g] = ev1 * silu(q1);
            }
        }
        __syncthreads();
        if (t < 32 && zsl[t] != 0.f) atomicAdd(&ws[WS_ZSUM + t], zsl[t]);
        #pragma unroll
        for (int it = 0; it < TPB; ++it) {
            int n0 = (blockIdx.x * TPB + it) * NPB;
            int count = NN - n0; if (count > NPB) count = NPB;
            int bf = Lb[it][0], bl = Lb[it][count - 1];
            int sh = t & 15, dp = t >> 4;
            for (int b2 = bf; b2 <= bl; ++b2) {
                float a0 = 0.f, a1 = 0.f;
                for (int i = 0; i < count; ++i) {
                    if (Lb[it][i] != b2) continue;
                    float w = Lw[it][i * 17 + sh];
                    float2 x = *(const float2*)(Fl[it] + i * 36 + 2 * dp);
                    a0 += w * x.x;
                    a1 += w * x.y;
                }
                float* Tb = ws + WS_T + b2 * 512 + sh * 32 + 2 * dp;
                atomicAdd(&Tb[0], a0);
                atomicAdd(&Tb[1], a1);
            }
        }
    }
    if (coop) cg::this_grid().sync();

    // ---------------- B: dummy_new -> AKG/AVG (blocks 0..31)
    if (do_b && blockIdx.x < 32) {
        int bb = blockIdx.x >> 1, s = blockIdx.x & 1;
        Tl[t] = ws[WS_T + bb * 512 + s * 256 + t];
        __syncthreads();
        {
            int h = t >> 5, e = t & 31;
            float acc = 0.f;
            #pragma unroll
            for (int d = 0; d < 32; ++d) acc += Tl[h * 32 + d] * W2_vd[h * 1024 + d * 32 + e];
            part[t] = acc;
        }
        __syncthreads();
        if (t < 32) {
            float acc = 0.f;
            #pragma unroll
            for (int h = 0; h < 8; ++h) acc += part[h * 32 + t];
            float zs = ws[WS_ZSUM + bb * 2 + s];
            dn[t] = init_dummy[t] + acc / zs;
        }
        __syncthreads();
        {
            int h = t >> 5, e = t & 31;
            float ak = 0.f, av = 0.f;
            #pragma unroll
            for (int d = 0; d < 32; ++d) {
                float dv = dn[d];
                ak += dv * W2_kg[h * 1024 + d * 32 + e];
                av += dv * W2_vg[h * 1024 + d * 32 + e];
            }
            ws[WS_AKG + bb * 512 + s * 256 + t] = ak;
            ws[WS_AVG + bb * 512 + s * 256 + t] = av;
        }
    }
    if (coop) cg::this_grid().sync();

    // ---------------- C: per-node output
    if (do_c) {
        const float4* Ak4 = (const float4*)(ws + WS_AKG);
        const float4* Av4 = (const float4*)(ws + WS_AVG);
        const float4* Wc4 = (const float4*)Wc;
        #pragma unroll
        for (int it = 0; it < TPB; ++it) {
            if (val[it]) {
                int b = bseg[it];
                float ak0, ak1, av0, av1;
                {
                    float pk0 = 0.f, pk1 = 0.f, pv0 = 0.f, pv1 = 0.f;
                    #pragma unroll
                    for (int k = 0; k < 8; ++k) {
                        float wk = W1kg[k * 8 + g];
                        float wv = W1vg[k * 8 + g];
                        pk0 += edge[it][0][k] * wk; pk1 += edge[it][1][k] * wk;
                        pv0 += edge[it][0][k] * wv; pv1 += edge[it][1][k] * wv;
                    }
                    ak0 = silu(pk0); ak1 = silu(pk1);
                    av0 = silu(pv0); av1 = silu(pv1);
                }
                float4 q4 = make_float4(0.f, 0.f, 0.f, 0.f);
                const float* myF = Fl[it] + li * 36;
                #pragma unroll
                for (int d = 0; d < 32; ++d) {
                    float fd = myF[d];
                    float4 w = Wc4[d * 8 + g];
                    q4.x += fd * w.x; q4.y += fd * w.y; q4.z += fd * w.z; q4.w += fd * w.w;
                }
                float p0 = 0.f, p1 = 0.f;
                #pragma unroll
                for (int h = 0; h < 8; ++h) {
                    float4 a0 = Ak4[b * 128 + h * 8 + g];
                    float4 a1 = Ak4[b * 128 + 64 + h * 8 + g];
                    float d0 = q4.x * a0.x + q4.y * a0.y + q4.z * a0.z + q4.w * a0.w;
                    float d1 = q4.x * a1.x + q4.y * a1.y + q4.z * a1.z + q4.w * a1.w;
                    p0 += __shfl(ak0, lanebase + h, 64) * d0;
                    p1 += __shfl(ak1, lanebase + h, 64) * d1;
                }
                #pragma unroll
                for (int m = 1; m < 8; m <<= 1) {
                    p0 += __shfl_xor(p0, m, 64);
                    p1 += __shfl_xor(p1, m, 64);
                }
                float sg0 = p0 * SCALE_C, sg1 = p1 * SCALE_C;
                float mm = fmaxf(sg0, sg1);
                float e0 = expf(sg0 - mm), e1 = expf(sg1 - mm);
                float inv = 1.0f / (e0 + e1);
                float ag0 = e0 * inv, ag1 = e1 * inv;

                float4 x4 = fv4[it];
                #pragma unroll
                for (int h = 0; h < 8; ++h) {
                    float w0 = ag0 * __shfl(av0, lanebase + h, 64);
                    float w1 = ag1 * __shfl(av1, lanebase + h, 64);
                    float4 a0 = Av4[b * 128 + h * 8 + g];
                    float4 a1 = Av4[b * 128 + 64 + h * 8 + g];
                    x4.x += w0 * a0.x + w1 * a1.x;
                    x4.y += w0 * a0.y + w1 * a1.y;
                    x4.z += w0 * a0.z + w1 * a1.z;
                    x4.w += w0 * a0.w + w1 * a1.w;
                }
                int n = (blockIdx.x * TPB + it) * NPB + li;
                ((float4*)out)[n * 8 + g] = x4;
            }
        }
    }
}

extern "C" void kernel_launch(void* const* d_in, const int* in_sizes, int n_in,
                              void* d_out, int out_size, void* d_ws, size_t ws_size,
                              hipStream_t stream) {
    const float* pos        = (const float*)d_in[0];
    const float* nf         = (const float*)d_in[1];
    const int*   batch      = (const int*)d_in[2];
    const float* bw         = (const float*)d_in[3];
    const float* init_dummy = (const float*)d_in[4];
    const float* Wq_dummy   = (const float*)d_in[5];
    const float* Wq_graph   = (const float*)d_in[6];
    const float* Wdot       = (const float*)d_in[7];
    const float* W1_kd      = (const float*)d_in[8];
    const float* W2_kd      = (const float*)d_in[9];
    const float* W1_vd      = (const float*)d_in[10];
    const float* W2_vd      = (const float*)d_in[11];
    const float* W1_kg      = (const float*)d_in[12];
    const float* W2_kg      = (const float*)d_in[13];
    const float* W1_vg      = (const float*)d_in[14];
    const float* W2_vg      = (const float*)d_in[15];
    float* ws  = (float*)d_ws;
    float* out = (float*)d_out;

    // capture-safe, host-only queries; cached
    static int coop_ok = -1;
    if (coop_ok < 0) {
        int dev = 0;
        (void)hipGetDevice(&dev);
        int attr = 0;
        (void)hipDeviceGetAttribute(&attr, hipDeviceAttributeCooperativeLaunch, dev);
        int maxb = 0;
        (void)hipOccupancyMaxActiveBlocksPerMultiprocessor(
            &maxb, reinterpret_cast<const void*>(&k_main), 256, 0);
        hipDeviceProp_t prop;
        (void)hipGetDeviceProperties(&prop, dev);
        coop_ok = (attr != 0 && maxb * prop.multiProcessorCount >= GRID) ? 1 : 0;
    }

    if (coop_ok == 1) {
        int mode = M_ALL;
        void* args[] = { (void*)&pos, (void*)&batch, (void*)&nf, (void*)&bw,
                         (void*)&W1_kd, (void*)&W1_vd, (void*)&W1_kg, (void*)&W1_vg,
                         (void*)&init_dummy, (void*)&Wq_dummy, (void*)&Wdot, (void*)&W2_kd,
                         (void*)&W2_vd, (void*)&W2_kg, (void*)&W2_vg, (void*)&Wq_graph,
                         (void*)&ws, (void*)&out, (void*)&mode };
        hipError_t err = hipLaunchCooperativeKernel((const void*)k_main, dim3(GRID), dim3(256),
                                                    args, 0, stream);
        if (err == hipSuccess) return;
        coop_ok = 0;  // fall through to split path
    }

    // fallback: same kernel, phase-split into 5 plain launches
    hipLaunchKernelGGL(k_main, dim3(GRID), dim3(256), 0, stream,
                       pos, batch, nf, bw, W1_kd, W1_vd, W1_kg, W1_vg,
                       init_dummy, Wq_dummy, Wdot, W2_kd, W2_vd, W2_kg, W2_vg, Wq_graph,
                       ws, out, M_PRE);
    hipLaunchKernelGGL(k_main, dim3(16), dim3(256), 0, stream,
                       pos, batch, nf, bw, W1_kd, W1_vd, W1_kg, W1_vg,
                       init_dummy, Wq_dummy, Wdot, W2_kd, W2_vd, W2_kg, W2_vg, Wq_graph,
                       ws, out, M_RED);
    hipLaunchKernelGGL(k_main, dim3(GRID), dim3(256), 0, stream,
                       pos, batch, nf, bw, W1_kd, W1_vd, W1_kg, W1_vg,
                       init_dummy, Wq_dummy, Wdot, W2_kd, W2_vd, W2_kg, W2_vg, Wq_graph,
                       ws, out, M_A);
    hipLaunchKernelGGL(k_main, dim3(32), dim3(256), 0, stream,
                       pos, batch, nf, bw, W1_kd, W1_vd, W1_kg, W1_vg,
                       init_dummy, Wq_dummy, Wdot, W2_kd, W2_vd, W2_kg, W2_vg, Wq_graph,
                       ws, out, M_B);
    hipLaunchKernelGGL(k_main, dim3(GRID), dim3(256), 0, stream,
                       pos, batch, nf, bw, W1_kd, W1_vd, W1_kg, W1_vg,
                       init_dummy, Wq_dummy, Wdot, W2_kd, W2_vd, W2_kg, W2_vg, Wq_graph,
                       ws, out, M_C);
}

// Round 4
// 136.748 us; speedup vs baseline: 1.0386x; 1.0386x over previous
//
#include <hip/hip_runtime.h>
#include <math.h>

#define NN 30000
#define DIST_C 5.0f
#define EPS_C 1e-6f
#define SCALE_C 0.17677669529663687f  // 1/sqrt(32)

// workspace float offsets (region below zeroed by memset each launch)
#define WS_ZSUM 0      // 32 f   [b*2+s]
#define WS_T    32     // 8192 f [b*512 + (s*8+h)*32 + d]
#define WS_CTR  8224   // 16 u32 per-batch arrival counters
#define WS_ZERO_BYTES ((8224 + 16) * 4)

__device__ __forceinline__ float silu(float x) { return x / (1.0f + expf(-x)); }

// edge[s][k] = sin(bw_k*x_s)/(x_s+eps); bw_k=(k+1)*bw0. Chebyshev recurrence:
// s_{k+1} = 2cos(th)*s_k - s_{k-1}.
__device__ __forceinline__ void bessel_edges(float bw0, float x0, float x1, float edge[2][8]) {
    float xs[2]; xs[0] = x0; xs[1] = x1;
#pragma unroll
    for (int s = 0; s < 2; ++s) {
        float x = xs[s];
        float inv = 1.0f / (x + EPS_C);
        float th = bw0 * x;
        float c2 = 2.0f * cosf(th);
        float skm1 = 0.0f;
        float sk = sinf(th);
#pragma unroll
        for (int k = 0; k < 8; ++k) {
            edge[s][k] = sk * inv;
            float nx = c2 * sk - skm1;
            skm1 = sk; sk = nx;
        }
    }
}

// One kernel. Grid = 16 * bpb blocks; block handles a slice of ONE batch.
// b = blockIdx.x % 16 (so CU-paired blocks serve different batches),
// m = blockIdx.x / 16. All blocks co-resident (launch_bounds(256,2), grid<=512)
// -> per-batch atomic-counter barrier is deadlock-free without coop launch.
__global__ __launch_bounds__(256, 2) void k_mega(
    const float* __restrict__ pos, const int* __restrict__ batch,
    const float* __restrict__ nf, const float* __restrict__ bw,
    const float* __restrict__ W1_kd, const float* __restrict__ W1_vd,
    const float* __restrict__ W1_kg, const float* __restrict__ W1_vg,
    const float* __restrict__ init_dummy, const float* __restrict__ Wq_dummy,
    const float* __restrict__ Wdot, const float* __restrict__ W2_kd,
    const float* __restrict__ W2_vd, const float* __restrict__ W2_kg,
    const float* __restrict__ W2_vg, const float* __restrict__ Wq_graph,
    float* __restrict__ ws, float* __restrict__ out, int bpb)
{
    __shared__ int bnd[17];
    __shared__ float Wdl[1024];
    __shared__ float qvec[32], qWl[32];
    __shared__ __align__(16) float Pk[256];
    __shared__ __align__(16) float Wc[1024];
    __shared__ float W1kd[64], W1vd[64], W1kg[64], W1vg[64];
    __shared__ __align__(16) float Fl[32 * 36];
    __shared__ float Lw[32 * 17];
    __shared__ float zred[8];
    __shared__ float zfin[2];
    __shared__ float Tl[512], part[512], dn[64];
    __shared__ __align__(16) float AKGl[512], AVGl[512];

    int t = threadIdx.x;
    int b = blockIdx.x & 15;
    int m = blockIdx.x >> 4;
    int li = t >> 3, g = t & 7;
    int lanebase = (t & 63) & 56;
    float bw0 = bw[0];

    // ---- startup: segment boundaries (batch sorted), weight staging, qvec
    if (t < 17) {
        int lo = 0, hi = NN;
        while (lo < hi) { int mid = (lo + hi) >> 1; if (batch[mid] < t) lo = mid + 1; else hi = mid; }
        bnd[t] = lo;
    }
    for (int i = t; i < 1024; i += 256) Wdl[i] = Wdot[i];
    if (t < 64) { W1kd[t] = W1_kd[t]; W1vd[t] = W1_vd[t]; W1kg[t] = W1_kg[t]; W1vg[t] = W1_vg[t]; }
    if (t < 32) {
        float acc = 0.f;
        for (int d = 0; d < 32; ++d) acc += init_dummy[d] * Wq_dummy[d * 32 + t];
        qvec[t] = acc;
    }
    __syncthreads();
    int s0 = bnd[b], s1 = bnd[b + 1];

    // ---- z min/max over my whole batch (redundant per block, no barrier) + qW
    {
        float zmn = 3.4e38f, zmx = -3.4e38f;
        for (int i = s0 + t; i < s1; i += 256) {
            float zz = pos[3 * i + 2];
            zmn = fminf(zmn, zz); zmx = fmaxf(zmx, zz);
        }
#pragma unroll
        for (int off = 1; off < 64; off <<= 1) {
            zmn = fminf(zmn, __shfl_xor(zmn, off, 64));
            zmx = fmaxf(zmx, __shfl_xor(zmx, off, 64));
        }
        if ((t & 63) == 0) { zred[(t >> 6) * 2] = zmn; zred[(t >> 6) * 2 + 1] = zmx; }
    }
    if (t < 32) {
        float acc = 0.f;
        for (int e = 0; e < 32; ++e) acc += qvec[e] * Wdl[e * 32 + t];
        qWl[t] = acc;
    }
    __syncthreads();
    if (t == 0) {
        zfin[0] = fminf(fminf(zred[0], zred[2]), fminf(zred[4], zred[6]));
        zfin[1] = fmaxf(fmaxf(zred[1], zred[3]), fmaxf(zred[5], zred[7]));
    }
    {   // Pk[h][d] = sum_e W2_kd[h, d*32+e] * qW[e]
        int h = t >> 5, d = t & 31;
        float acc = 0.f;
        for (int e = 0; e < 32; ++e) acc += W2_kd[h * 1024 + d * 32 + e] * qWl[e];
        Pk[t] = acc;
    }
    __syncthreads();
    float zminb = zfin[0], zmaxb = zfin[1];

    // ---- phase A: my node slice [s0+m*32, s1) stride bpb*32
    float tAcc0 = 0.f, tAcc1 = 0.f, zsA0 = 0.f, zsA1 = 0.f;
    int sh = t & 15, dp = t >> 4;
    int stride = bpb * 32;
    for (int base = s0 + m * 32; base < s1; base += stride) {
        int cnt = s1 - base; if (cnt > 32) cnt = 32;
        if (li < cnt) {
            int n = base + li;
            float4 fv4 = ((const float4*)nf)[n * 8 + g];
            ((float4*)(Fl + li * 36))[g] = fv4;
            float z = pos[3 * n + 2];
            float edge[2][8];
            bessel_edges(bw0, z - zminb + DIST_C, zmaxb + DIST_C - z, edge);
            float up[8];
            const float4* Pk4 = (const float4*)Pk;
#pragma unroll
            for (int h = 0; h < 8; ++h) {
                float4 p = Pk4[h * 8 + g];
                up[h] = fv4.x * p.x + fv4.y * p.y + fv4.z * p.z + fv4.w * p.w;
            }
            float p0 = 0.f, p1 = 0.f;
#pragma unroll
            for (int k = 0; k < 8; ++k) {
                float w = W1kd[k * 8 + g];
                p0 += edge[0][k] * w; p1 += edge[1][k] * w;
            }
            float kd0 = silu(p0), kd1 = silu(p1);
            float sp0 = 0.f, sp1 = 0.f;
#pragma unroll
            for (int h = 0; h < 8; ++h) {
                sp0 += __shfl(kd0, lanebase + h, 64) * up[h];
                sp1 += __shfl(kd1, lanebase + h, 64) * up[h];
            }
#pragma unroll
            for (int mm = 1; mm < 8; mm <<= 1) {
                sp0 += __shfl_xor(sp0, mm, 64);
                sp1 += __shfl_xor(sp1, mm, 64);
            }
            float ev0 = expf(sp0 * SCALE_C);
            float ev1 = expf(sp1 * SCALE_C);
            if (g == 0) { zsA0 += ev0; zsA1 += ev1; }
            float q0 = 0.f, q1 = 0.f;
#pragma unroll
            for (int k = 0; k < 8; ++k) {
                float w = W1vd[k * 8 + g];
                q0 += edge[0][k] * w; q1 += edge[1][k] * w;
            }
            Lw[li * 17 + g] = ev0 * silu(q0);
            Lw[li * 17 + 8 + g] = ev1 * silu(q1);
        }
        __syncthreads();
        for (int i = 0; i < cnt; ++i) {   // outer-product reduce (all nodes are batch b)
            float w = Lw[i * 17 + sh];
            float2 x = *(const float2*)(Fl + i * 36 + 2 * dp);
            tAcc0 += w * x.x; tAcc1 += w * x.y;
        }
        __syncthreads();
    }
    {
        float* Tb = ws + WS_T + b * 512 + sh * 32 + 2 * dp;
        atomicAdd(&Tb[0], tAcc0);
        atomicAdd(&Tb[1], tAcc1);
#pragma unroll
        for (int off = 1; off < 64; off <<= 1) {   // g!=0 lanes hold 0
            zsA0 += __shfl_xor(zsA0, off, 64);
            zsA1 += __shfl_xor(zsA1, off, 64);
        }
        if ((t & 63) == 0) { zred[(t >> 6) * 2] = zsA0; zred[(t >> 6) * 2 + 1] = zsA1; }
    }
    __syncthreads();
    if (t == 0) {
        atomicAdd(ws + WS_ZSUM + b * 2,     zred[0] + zred[2] + zred[4] + zred[6]);
        atomicAdd(ws + WS_ZSUM + b * 2 + 1, zred[1] + zred[3] + zred[5] + zred[7]);
    }
    __syncthreads();

    // ---- per-batch barrier (bpb blocks); compute Wc while waiting
    unsigned* ctru = (unsigned*)(ws + WS_CTR);
    if (t == 0) { __threadfence(); atomicAdd(&ctru[b], 1u); }
    for (int i = t; i < 1024; i += 256) {   // Wc = Wq_graph @ Wdot
        int d = i >> 5, e = i & 31;
        float acc = 0.f;
        for (int mm = 0; mm < 32; ++mm) acc += Wq_graph[d * 32 + mm] * Wdl[mm * 32 + e];
        Wc[i] = acc;
    }
    if (t == 0) {
        int guard = 0;
        while (__hip_atomic_load(&ctru[b], __ATOMIC_ACQUIRE, __HIP_MEMORY_SCOPE_AGENT)
               < (unsigned)bpb) {
            __builtin_amdgcn_s_sleep(8);
            if (++guard > (1 << 26)) break;   // defensive; never expected
        }
    }
    __syncthreads();

    // ---- phase B (redundant per block; AKG/AVG stay in LDS)
    Tl[t]       = __hip_atomic_load(ws + WS_T + b * 512 + t,       __ATOMIC_RELAXED, __HIP_MEMORY_SCOPE_AGENT);
    Tl[256 + t] = __hip_atomic_load(ws + WS_T + b * 512 + 256 + t, __ATOMIC_RELAXED, __HIP_MEMORY_SCOPE_AGENT);
    if (t == 0) {
        zfin[0] = __hip_atomic_load(ws + WS_ZSUM + b * 2,     __ATOMIC_RELAXED, __HIP_MEMORY_SCOPE_AGENT);
        zfin[1] = __hip_atomic_load(ws + WS_ZSUM + b * 2 + 1, __ATOMIC_RELAXED, __HIP_MEMORY_SCOPE_AGENT);
    }
    __syncthreads();
    {
        int h = t >> 5, e = t & 31;
        float a0 = 0.f, a1 = 0.f;
        for (int d = 0; d < 32; ++d) {
            float w2 = W2_vd[h * 1024 + d * 32 + e];
            a0 += Tl[h * 32 + d] * w2;
            a1 += Tl[256 + h * 32 + d] * w2;
        }
        part[t] = a0; part[256 + t] = a1;
    }
    __syncthreads();
    if (t < 64) {
        int s = t >> 5, dd = t & 31;
        float acc = 0.f;
        for (int h = 0; h < 8; ++h) acc += part[s * 256 + h * 32 + dd];
        dn[t] = init_dummy[dd] + acc / zfin[s];
    }
    __syncthreads();
    {
        int h = t >> 5, e = t & 31;
        float ak0 = 0.f, av0 = 0.f, ak1 = 0.f, av1 = 0.f;
        for (int d = 0; d < 32; ++d) {
            float w2k = W2_kg[h * 1024 + d * 32 + e];
            float w2v = W2_vg[h * 1024 + d * 32 + e];
            ak0 += dn[d] * w2k;      av0 += dn[d] * w2v;
            ak1 += dn[32 + d] * w2k; av1 += dn[32 + d] * w2v;
        }
        AKGl[t] = ak0; AKGl[256 + t] = ak1;
        AVGl[t] = av0; AVGl[256 + t] = av1;
    }
    __syncthreads();

    // ---- phase C: per-node output over the same slice
    const float4* Ak4 = (const float4*)AKGl;
    const float4* Av4 = (const float4*)AVGl;
    const float4* Wc4 = (const float4*)Wc;
    for (int base = s0 + m * 32; base < s1; base += stride) {
        int cnt = s1 - base; if (cnt > 32) cnt = 32;
        float4 fv4 = make_float4(0.f, 0.f, 0.f, 0.f);
        float z = 0.f;
        if (li < cnt) {
            int n = base + li;
            fv4 = ((const float4*)nf)[n * 8 + g];
            ((float4*)(Fl + li * 36))[g] = fv4;
            z = pos[3 * n + 2];
        }
        __syncthreads();
        if (li < cnt) {
            float edge[2][8];
            bessel_edges(bw0, z - zminb + DIST_C, zmaxb + DIST_C - z, edge);
            float sk0, sk1, sv0, sv1;
            {
                float pk0 = 0.f, pk1 = 0.f, pv0 = 0.f, pv1 = 0.f;
#pragma unroll
                for (int k = 0; k < 8; ++k) {
                    float wk = W1kg[k * 8 + g];
                    float wv = W1vg[k * 8 + g];
                    pk0 += edge[0][k] * wk; pk1 += edge[1][k] * wk;
                    pv0 += edge[0][k] * wv; pv1 += edge[1][k] * wv;
                }
                sk0 = silu(pk0); sk1 = silu(pk1);
                sv0 = silu(pv0); sv1 = silu(pv1);
            }
            float4 q4 = make_float4(0.f, 0.f, 0.f, 0.f);
            const float* myF = Fl + li * 36;
#pragma unroll
            for (int d = 0; d < 32; ++d) {
                float fd = myF[d];
                float4 w = Wc4[d * 8 + g];
                q4.x += fd * w.x; q4.y += fd * w.y; q4.z += fd * w.z; q4.w += fd * w.w;
            }
            float p0 = 0.f, p1 = 0.f;
#pragma unroll
            for (int h = 0; h < 8; ++h) {
                float4 a0 = Ak4[h * 8 + g];
                float4 a1 = Ak4[64 + h * 8 + g];
                float d0 = q4.x * a0.x + q4.y * a0.y + q4.z * a0.z + q4.w * a0.w;
                float d1 = q4.x * a1.x + q4.y * a1.y + q4.z * a1.z + q4.w * a1.w;
                p0 += __shfl(sk0, lanebase + h, 64) * d0;
                p1 += __shfl(sk1, lanebase + h, 64) * d1;
            }
#pragma unroll
            for (int mm = 1; mm < 8; mm <<= 1) {
                p0 += __shfl_xor(p0, mm, 64);
                p1 += __shfl_xor(p1, mm, 64);
            }
            float sg0 = p0 * SCALE_C, sg1 = p1 * SCALE_C;
            float mx = fmaxf(sg0, sg1);
            float e0 = expf(sg0 - mx), e1 = expf(sg1 - mx);
            float inv = 1.0f / (e0 + e1);
            float ag0 = e0 * inv, ag1 = e1 * inv;
            float4 x4 = fv4;
#pragma unroll
            for (int h = 0; h < 8; ++h) {
                float w0 = ag0 * __shfl(sv0, lanebase + h, 64);
                float w1 = ag1 * __shfl(sv1, lanebase + h, 64);
                float4 a0 = Av4[h * 8 + g];
                float4 a1 = Av4[64 + h * 8 + g];
                x4.x += w0 * a0.x + w1 * a1.x;
                x4.y += w0 * a0.y + w1 * a1.y;
                x4.z += w0 * a0.z + w1 * a1.z;
                x4.w += w0 * a0.w + w1 * a1.w;
            }
            int n = base + li;
            ((float4*)out)[n * 8 + g] = x4;
        }
        __syncthreads();
    }
}

extern "C" void kernel_launch(void* const* d_in, const int* in_sizes, int n_in,
                              void* d_out, int out_size, void* d_ws, size_t ws_size,
                              hipStream_t stream) {
    const float* pos        = (const float*)d_in[0];
    const float* nf         = (const float*)d_in[1];
    const int*   batch      = (const int*)d_in[2];
    const float* bw         = (const float*)d_in[3];
    const float* init_dummy = (const float*)d_in[4];
    const float* Wq_dummy   = (const float*)d_in[5];
    const float* Wq_graph   = (const float*)d_in[6];
    const float* Wdot       = (const float*)d_in[7];
    const float* W1_kd      = (const float*)d_in[8];
    const float* W2_kd      = (const float*)d_in[9];
    const float* W1_vd      = (const float*)d_in[10];
    const float* W2_vd      = (const float*)d_in[11];
    const float* W1_kg      = (const float*)d_in[12];
    const float* W2_kg      = (const float*)d_in[13];
    const float* W1_vg      = (const float*)d_in[14];
    const float* W2_vg      = (const float*)d_in[15];
    float* ws  = (float*)d_ws;
    float* out = (float*)d_out;

    // capture-safe host query, cached: blocks-per-batch such that the whole
    // grid is guaranteed co-resident (spin barrier safety).
    static int bpb_cached = -1;
    if (bpb_cached < 0) {
        int maxb = 0;
        hipError_t e = hipOccupancyMaxActiveBlocksPerMultiprocessor(
            &maxb, reinterpret_cast<const void*>(k_mega), 256, 0);
        bpb_cached = (e == hipSuccess && maxb >= 2) ? 32 : 16;
    }

    hipMemsetAsync(ws, 0, WS_ZERO_BYTES, stream);
    hipLaunchKernelGGL(k_mega, dim3(16 * bpb_cached), dim3(256), 0, stream,
                       pos, batch, nf, bw, W1_kd, W1_vd, W1_kg, W1_vg,
                       init_dummy, Wq_dummy, Wdot, W2_kd, W2_vd, W2_kg, W2_vg, Wq_graph,
                       ws, out, bpb_cached);
}